// Round 12
// baseline (334.196 us; speedup 1.0000x reference)
//
#include <hip/hip_runtime.h>
#include <hip/hip_fp16.h>

#define N_NODES 50000
#define N_EDGES 800000
#define HID 128
#define OUT_CH 64
#define NB_SCAN 196   // ceil(50000/256)
#define NBUCK 196     // dst buckets of 256 nodes
#define EPT 8         // edges per thread in bucket_scatter

typedef __attribute__((ext_vector_type(8))) _Float16 half8;
typedef __attribute__((ext_vector_type(4))) float floatx4;

// ---------------- graph preprocessing ----------------

__global__ void prep_init(int* __restrict__ counts, float* __restrict__ sum,
                          int* __restrict__ bucket_cnt) {
    int i = blockIdx.x * blockDim.x + threadIdx.x;
    if (i < N_NODES) counts[i] = 0;
    if (i < OUT_CH) sum[i] = 0.0f;
    if (i < NBUCK) bucket_cnt[i] = 0;
}

__global__ __launch_bounds__(256)
void count_edges(const int* __restrict__ ei, int* __restrict__ counts,
                 int* __restrict__ bucket_cnt) {
    __shared__ int h[NBUCK];
    const int tid = threadIdx.x;
    for (int i = tid; i < NBUCK; i += 256) h[i] = 0;
    __syncthreads();
    int e = blockIdx.x * 256 + tid;
    if (e < N_EDGES) {
        int c = ei[N_EDGES + e];
        atomicAdd(&counts[c], 1);
        atomicAdd(&h[c >> 8], 1);
    }
    __syncthreads();
    for (int i = tid; i < NBUCK; i += 256)
        if (h[i]) atomicAdd(&bucket_cnt[i], h[i]);
}

__global__ __launch_bounds__(256)
void scan_blocks(const int* __restrict__ counts, int* __restrict__ row_start,
                 int* __restrict__ bsum) {
    __shared__ int s[256];
    int tid = threadIdx.x;
    int i = blockIdx.x * 256 + tid;
    int v = (i < N_NODES) ? counts[i] : 0;
    s[tid] = v;
    __syncthreads();
    for (int off = 1; off < 256; off <<= 1) {
        int t = (tid >= off) ? s[tid - off] : 0;
        __syncthreads();
        s[tid] += t;
        __syncthreads();
    }
    if (i < N_NODES) row_start[i] = s[tid] - v;  // exclusive
    if (tid == 255) bsum[blockIdx.x] = s[255];
}

// scans both the 196 block-sums (for row_start) and the 196 bucket counts
__global__ __launch_bounds__(256)
void scan_bsums(int* __restrict__ bsum, const int* __restrict__ bucket_cnt,
                int* __restrict__ bucket_off, int* __restrict__ bucket_cur) {
    __shared__ int s[256];
    int tid = threadIdx.x;
    int v = (tid < NB_SCAN) ? bsum[tid] : 0;
    s[tid] = v;
    __syncthreads();
    for (int off = 1; off < 256; off <<= 1) {
        int t = (tid >= off) ? s[tid - off] : 0;
        __syncthreads();
        s[tid] += t;
        __syncthreads();
    }
    if (tid < NB_SCAN) bsum[tid] = s[tid] - v;  // exclusive
    __syncthreads();
    int bv = (tid < NBUCK) ? bucket_cnt[tid] : 0;
    s[tid] = bv;
    __syncthreads();
    for (int off = 1; off < 256; off <<= 1) {
        int t = (tid >= off) ? s[tid - off] : 0;
        __syncthreads();
        s[tid] += t;
        __syncthreads();
    }
    if (tid < NBUCK) {
        int excl = s[tid] - bv;
        bucket_off[tid] = excl;
        bucket_cur[tid] = excl;
    }
    if (tid == 0) bucket_off[NBUCK] = N_EDGES;
}

__global__ void scan_fixup(int* __restrict__ row_start, const int* __restrict__ bsum,
                           const int* __restrict__ counts, float* __restrict__ dinv) {
    int i = blockIdx.x * blockDim.x + threadIdx.x;
    if (i < N_NODES) {
        row_start[i] += bsum[i >> 8];
        dinv[i] = rsqrtf(1.0f + (float)counts[i]);  // +1 self-loop
    }
    if (i == 0) row_start[N_NODES] = N_EDGES;
}

// scatter edges into 256-node dst buckets; per-(block,bucket) runs are reserved
// with one global atomic so writes land in block-exclusive contiguous regions.
__global__ __launch_bounds__(256)
void bucket_scatter(const int* __restrict__ ei, int* __restrict__ bucket_cur,
                    int2* __restrict__ brec) {
    __shared__ int hist[NBUCK];
    __shared__ int grun[NBUCK];
    const int tid = threadIdx.x;
    for (int i = tid; i < NBUCK; i += 256) hist[i] = 0;
    __syncthreads();
    const int e0 = blockIdx.x * (256 * EPT);
    int src[EPT], dst[EPT], rank[EPT], bk[EPT];
#pragma unroll
    for (int j = 0; j < EPT; j++) {
        int e = e0 + j * 256 + tid;
        if (e < N_EDGES) {
            src[j] = ei[e];
            dst[j] = ei[N_EDGES + e];
            bk[j] = dst[j] >> 8;
            rank[j] = atomicAdd(&hist[bk[j]], 1);
        } else {
            bk[j] = -1;
        }
    }
    __syncthreads();
    for (int i = tid; i < NBUCK; i += 256)
        grun[i] = hist[i] ? atomicAdd(&bucket_cur[i], hist[i]) : 0;
    __syncthreads();
#pragma unroll
    for (int j = 0; j < EPT; j++)
        if (bk[j] >= 0) brec[grun[bk[j]] + rank[j]] = make_int2(src[j], dst[j]);
}

// one block per bucket: finish per-node grouping; all writes for a node come
// from this single block (single XCD) -> L2 write-coalesced.
__global__ __launch_bounds__(256)
void node_sort(const int2* __restrict__ brec, const int* __restrict__ bucket_off,
               const int* __restrict__ row_start, int* __restrict__ esrc) {
    __shared__ int lcur[256];
    const int tid = threadIdx.x;
    lcur[tid] = 0;
    __syncthreads();
    const int b = blockIdx.x;
    const int i1 = bucket_off[b + 1];
    for (int i = bucket_off[b] + tid; i < i1; i += 256) {
        int2 rec = brec[i];
        int r = atomicAdd(&lcur[rec.y & 255], 1);
        esrc[row_start[rec.y] + r] = rec.x;
    }
}

// ---------------- fp16 prep ----------------

__global__ void convert_x(const float* __restrict__ x, _Float16* __restrict__ xh) {
    int i = blockIdx.x * 256 + threadIdx.x;   // one float4 per thread
    if (i < N_NODES * (HID / 4)) {
        float4 v = ((const float4*)x)[i];
        union { __half2 h2[2]; int2 i2; } u;
        u.h2[0] = __floats2half2_rn(v.x, v.y);
        u.h2[1] = __floats2half2_rn(v.z, v.w);
        ((int2*)xh)[i] = u.i2;
    }
}

// all four weights -> fp16, transposed to [N][K]
__global__ void wtrans_all(const float* __restrict__ W1, const float* __restrict__ W2,
                           const float* __restrict__ W3, const float* __restrict__ Wo,
                           _Float16* __restrict__ wt1, _Float16* __restrict__ wt2,
                           _Float16* __restrict__ wt3, _Float16* __restrict__ wto) {
    const int SZ = HID * HID;  // 16384
    int i = blockIdx.x * 256 + threadIdx.x;
    if (i < SZ) {
        int k = i >> 7, c = i & 127;
        wt1[(size_t)c * HID + k] = (_Float16)W1[i];
    } else if (i < 2 * SZ) {
        int j = i - SZ, k = j >> 7, c = j & 127;
        wt2[(size_t)c * HID + k] = (_Float16)W2[j];
    } else if (i < 3 * SZ) {
        int j = i - 2 * SZ, k = j >> 7, c = j & 127;
        wt3[(size_t)c * HID + k] = (_Float16)W3[j];
    } else if (i < 3 * SZ + HID * OUT_CH) {
        int j = i - 3 * SZ, k = j >> 6, c = j & 63;
        wto[(size_t)c * HID + k] = (_Float16)Wo[j];
    }
}

// ---------------- MFMA GEMM: Y[n][OUT] = A(fp16)[n][128] @ W, Wt is [OUT][128] ----------------
// Wave = 16 rows x 64 cols (4 16x16 tiles, K=128 -> 4 MFMA each). No LDS, no syncs.

template <int OUT, bool ADD_BIAS, bool SCALE, bool HALF_OUT>
__global__ __launch_bounds__(256)
void gemm_mfma(const _Float16* __restrict__ A, const _Float16* __restrict__ Wt,
               const float* __restrict__ bias, const float* __restrict__ dinv,
               void* __restrict__ Yv, int n) {
    const int tid  = threadIdx.x;
    const int lane = tid & 63;
    const int wv   = tid >> 6;
    const int m0   = blockIdx.x * 64 + wv * 16;
    if (m0 >= n) return;                       // n % 16 == 0: no partial bands
    const int l15  = lane & 15;
    const int kb   = lane >> 4;                // 0..3
    const int col0 = blockIdx.y * 64;

    const _Float16* arow = A + (size_t)(m0 + l15) * 128 + kb * 8;
    half8 a[4];
#pragma unroll
    for (int j = 0; j < 4; j++) a[j] = *(const half8*)(arow + j * 32);

    const int rbase = m0 + kb * 4;             // rows this lane's D covers
    float4 dv = make_float4(1.f, 1.f, 1.f, 1.f);
    if constexpr (SCALE) dv = *(const float4*)(dinv + rbase);
    const float ds[4] = {dv.x, dv.y, dv.z, dv.w};

#pragma unroll
    for (int nt = 0; nt < 4; nt++) {
        const int col = col0 + nt * 16 + l15;
        const _Float16* brow = Wt + (size_t)col * 128 + kb * 8;
        floatx4 acc = {0.f, 0.f, 0.f, 0.f};
#pragma unroll
        for (int j = 0; j < 4; j++) {
            half8 b = *(const half8*)(brow + j * 32);
            acc = __builtin_amdgcn_mfma_f32_16x16x32_f16(a[j], b, acc, 0, 0, 0);
        }
        if constexpr (HALF_OUT) {
            _Float16* Y = (_Float16*)Yv;
#pragma unroll
            for (int r = 0; r < 4; r++)
                Y[(size_t)(rbase + r) * OUT + col] = (_Float16)(acc[r] * ds[r]);
        } else {
            float* Y = (float*)Yv;
            float bc = ADD_BIAS ? bias[col] : 0.f;
#pragma unroll
            for (int r = 0; r < 4; r++)
                Y[(size_t)(rbase + r) * OUT + col] = acc[r] + bc;
        }
    }
}

// ---------------- fused aggregation ----------------
// t is dinv-pre-scaled fp16. out[c] = relu(dinv[c]*(t[c] + sum_src t[src]) + b), fp16.

__global__ __launch_bounds__(256)
void aggregate_h(const _Float16* __restrict__ t, const int* __restrict__ row_start,
                 const int* __restrict__ esrc, const float* __restrict__ dinv,
                 const float* __restrict__ bias, _Float16* __restrict__ out) {
    const int tid = threadIdx.x;
    const int node = blockIdx.x * 8 + (tid >> 5);
    const int f4 = tid & 31;   // features 4*f4 .. 4*f4+3
    if (node >= N_NODES) return;

    const int2* t2 = (const int2*)t;

    int2 sg = t2[(size_t)node * 32 + f4];       // self term (pre-scaled)
    float2 slo = __half22float2(*(__half2*)&sg.x);
    float2 shi = __half22float2(*(__half2*)&sg.y);
    float4 acc = make_float4(slo.x, slo.y, shi.x, shi.y);

    int k = row_start[node];
    const int k1 = row_start[node + 1];
    for (; k + 8 <= k1; k += 8) {
        int src[8];
#pragma unroll
        for (int u = 0; u < 8; u++) src[u] = esrc[k + u];
        int2 g[8];
#pragma unroll
        for (int u = 0; u < 8; u++) g[u] = t2[(size_t)src[u] * 32 + f4];
#pragma unroll
        for (int u = 0; u < 8; u++) {
            float2 lo = __half22float2(*(__half2*)&g[u].x);
            float2 hi = __half22float2(*(__half2*)&g[u].y);
            acc.x += lo.x;
            acc.y += lo.y;
            acc.z += hi.x;
            acc.w += hi.y;
        }
    }
    for (; k < k1; k++) {
        int2 g = t2[(size_t)esrc[k] * 32 + f4];
        float2 lo = __half22float2(*(__half2*)&g.x);
        float2 hi = __half22float2(*(__half2*)&g.y);
        acc.x += lo.x;
        acc.y += lo.y;
        acc.z += hi.x;
        acc.w += hi.y;
    }

    const float d = dinv[node];
    float4 b = ((const float4*)bias)[f4];
    acc.x = fmaxf(acc.x * d + b.x, 0.f);
    acc.y = fmaxf(acc.y * d + b.y, 0.f);
    acc.z = fmaxf(acc.z * d + b.z, 0.f);
    acc.w = fmaxf(acc.w * d + b.w, 0.f);

    union { __half2 h2[2]; int2 i2; } u;
    u.h2[0] = __floats2half2_rn(acc.x, acc.y);
    u.h2[1] = __floats2half2_rn(acc.z, acc.w);
    ((int2*)out)[(size_t)node * 32 + f4] = u.i2;
}

// ---------------- mean pool ----------------

__global__ __launch_bounds__(256)
void mean_partial(const float* __restrict__ P, float* __restrict__ sum) {
    __shared__ float red[256];
    const int tid = threadIdx.x;
    const int c = tid & 63;
    const int grp = tid >> 6;
    float acc = 0.0f;
    for (int r = blockIdx.x * 4 + grp; r < N_NODES; r += gridDim.x * 4)
        acc += P[r * OUT_CH + c];
    red[tid] = acc;
    __syncthreads();
    if (grp == 0) {
        float s = red[c] + red[64 + c] + red[128 + c] + red[192 + c];
        atomicAdd(&sum[c], s);
    }
}

__global__ void mean_final(const float* __restrict__ sum, float* __restrict__ out) {
    int j = threadIdx.x;
    if (j < OUT_CH) out[N_NODES * OUT_CH + j] = sum[j] * (1.0f / N_NODES);
}

// ---------------- launch ----------------

extern "C" void kernel_launch(void* const* d_in, const int* in_sizes, int n_in,
                              void* d_out, int out_size, void* d_ws, size_t ws_size,
                              hipStream_t stream) {
    const float* x  = (const float*)d_in[0];
    const int* ei   = (const int*)d_in[1];   // int32 on device
    const float* W1 = (const float*)d_in[2];
    const float* b1 = (const float*)d_in[3];
    const float* W2 = (const float*)d_in[4];
    const float* b2 = (const float*)d_in[5];
    const float* W3 = (const float*)d_in[6];
    const float* b3 = (const float*)d_in[7];
    const float* Wo = (const float*)d_in[8];
    const float* bo = (const float*)d_in[9];
    float* out = (float*)d_out;

    char* ws = (char*)d_ws;
    auto take = [&](size_t bytes) {
        char* p = ws;
        ws += (bytes + 255) & ~size_t(255);
        return (void*)p;
    };
    int*      counts     = (int*)take((size_t)N_NODES * 4);
    int*      row_start  = (int*)take((size_t)(N_NODES + 1) * 4);
    int*      bsum       = (int*)take((size_t)NB_SCAN * 4);
    int*      bucket_cnt = (int*)take((size_t)NBUCK * 4);
    int*      bucket_off = (int*)take((size_t)(NBUCK + 1) * 4);
    int*      bucket_cur = (int*)take((size_t)NBUCK * 4);
    int2*     brec       = (int2*)take((size_t)N_EDGES * 8);
    float*    dinv       = (float*)take((size_t)N_NODES * 4);
    int*      esrc       = (int*)take((size_t)N_EDGES * 4);
    float*    sum        = (float*)take(OUT_CH * 4);
    _Float16* xh         = (_Float16*)take((size_t)N_NODES * HID * 2);
    _Float16* wt1        = (_Float16*)take((size_t)HID * HID * 2);
    _Float16* wt2        = (_Float16*)take((size_t)HID * HID * 2);
    _Float16* wt3       = (_Float16*)take((size_t)HID * HID * 2);
    _Float16* wto        = (_Float16*)take((size_t)HID * OUT_CH * 2);
    _Float16* hA         = (_Float16*)take((size_t)N_NODES * HID * 2);
    _Float16* hB         = (_Float16*)take((size_t)N_NODES * HID * 2);

    const int BS = 256;
    const int gN    = (N_NODES + BS - 1) / BS;
    const int gE    = (N_EDGES + BS - 1) / BS;
    const int gScat = (N_EDGES + BS * EPT - 1) / (BS * EPT);
    const int gGemm = (N_NODES + 63) / 64;
    const int gAgg  = (N_NODES + 7) / 8;
    const int gCvt  = (N_NODES * (HID / 4) + BS - 1) / BS;
    const int gWt   = (3 * HID * HID + HID * OUT_CH + BS - 1) / BS;

    // CSR build (bucketed, write-coalesced)
    prep_init<<<gN, BS, 0, stream>>>(counts, sum, bucket_cnt);
    count_edges<<<gE, BS, 0, stream>>>(ei, counts, bucket_cnt);
    scan_blocks<<<NB_SCAN, BS, 0, stream>>>(counts, row_start, bsum);
    scan_bsums<<<1, BS, 0, stream>>>(bsum, bucket_cnt, bucket_off, bucket_cur);
    scan_fixup<<<gN, BS, 0, stream>>>(row_start, bsum, counts, dinv);
    bucket_scatter<<<gScat, BS, 0, stream>>>(ei, bucket_cur, brec);
    node_sort<<<NBUCK, BS, 0, stream>>>(brec, bucket_off, row_start, esrc);

    // fp16 prep
    convert_x<<<gCvt, BS, 0, stream>>>(x, xh);
    wtrans_all<<<gWt, BS, 0, stream>>>(W1, W2, W3, Wo, wt1, wt2, wt3, wto);

    const _Float16* hin = xh;
    const _Float16* wts[3] = {wt1, wt2, wt3};
    const float* bs[3] = {b1, b2, b3};
    for (int layer = 0; layer < 3; layer++) {
        gemm_mfma<HID, false, true, true><<<dim3(gGemm, 2), BS, 0, stream>>>(
            hin, wts[layer], nullptr, dinv, hA, N_NODES);
        aggregate_h<<<gAgg, BS, 0, stream>>>(hA, row_start, esrc, dinv, bs[layer], hB);
        hin = hB;
    }

    gemm_mfma<OUT_CH, true, false, false><<<dim3(gGemm, 1), BS, 0, stream>>>(
        hB, wto, bo, nullptr, out, N_NODES);
    mean_partial<<<256, BS, 0, stream>>>(out, sum);
    mean_final<<<1, 64, 0, stream>>>(sum, out);
}

// Round 13
// 253.553 us; speedup vs baseline: 1.3181x; 1.3181x over previous
//
#include <hip/hip_runtime.h>
#include <hip/hip_fp16.h>

#define N_NODES 50000
#define N_EDGES 800000
#define HID 128
#define OUT_CH 64
#define NBUCK 196     // dst buckets of 256 nodes
#define HB 512        // blocks in bucket_hist
#define EPT 8         // edges per thread in bucket_scatter

typedef __attribute__((ext_vector_type(8))) _Float16 half8;
typedef __attribute__((ext_vector_type(4))) float floatx4;

// ---------------- graph preprocessing (no per-node global atomics) ----------------

// per-block LDS histogram of dst buckets; contention-free global writes
__global__ __launch_bounds__(256)
void bucket_hist(const int* __restrict__ ei, int* __restrict__ bhist) {
    __shared__ int h[NBUCK];
    const int tid = threadIdx.x;
    for (int i = tid; i < NBUCK; i += 256) h[i] = 0;
    __syncthreads();
    const int chunk = (N_EDGES + HB - 1) / HB;
    const int e0 = blockIdx.x * chunk;
    const int e1 = min(e0 + chunk, N_EDGES);
    for (int e = e0 + tid; e < e1; e += 256)
        atomicAdd(&h[ei[N_EDGES + e] >> 8], 1);
    __syncthreads();
    for (int i = tid; i < NBUCK; i += 256) bhist[blockIdx.x * NBUCK + i] = h[i];
}

// one block: reduce bhist columns, exclusive-scan -> bucket_off/cur; zero sum
__global__ __launch_bounds__(256)
void bucket_scan(const int* __restrict__ bhist, int* __restrict__ bucket_off,
                 int* __restrict__ bucket_cur, float* __restrict__ sum) {
    __shared__ int s[256];
    const int tid = threadIdx.x;
    if (tid < OUT_CH) sum[tid] = 0.0f;
    int v = 0;
    if (tid < NBUCK)
        for (int b = 0; b < HB; b++) v += bhist[b * NBUCK + tid];
    s[tid] = v;
    __syncthreads();
    for (int off = 1; off < 256; off <<= 1) {
        int t = (tid >= off) ? s[tid - off] : 0;
        __syncthreads();
        s[tid] += t;
        __syncthreads();
    }
    if (tid < NBUCK) {
        int excl = s[tid] - v;
        bucket_off[tid] = excl;
        bucket_cur[tid] = excl;
    }
    if (tid == 0) bucket_off[NBUCK] = N_EDGES;
}

// scatter edges into 256-node dst buckets; per-(block,bucket) runs reserved
// with one global atomic each so writes land in block-exclusive regions.
__global__ __launch_bounds__(256)
void bucket_scatter(const int* __restrict__ ei, int* __restrict__ bucket_cur,
                    int2* __restrict__ brec) {
    __shared__ int hist[NBUCK];
    __shared__ int grun[NBUCK];
    const int tid = threadIdx.x;
    for (int i = tid; i < NBUCK; i += 256) hist[i] = 0;
    __syncthreads();
    const int e0 = blockIdx.x * (256 * EPT);
    int src[EPT], dst[EPT], rank[EPT], bk[EPT];
#pragma unroll
    for (int j = 0; j < EPT; j++) {
        int e = e0 + j * 256 + tid;
        if (e < N_EDGES) {
            src[j] = ei[e];
            dst[j] = ei[N_EDGES + e];
            bk[j] = dst[j] >> 8;
            rank[j] = atomicAdd(&hist[bk[j]], 1);
        } else {
            bk[j] = -1;
        }
    }
    __syncthreads();
    for (int i = tid; i < NBUCK; i += 256)
        grun[i] = hist[i] ? atomicAdd(&bucket_cur[i], hist[i]) : 0;
    __syncthreads();
#pragma unroll
    for (int j = 0; j < EPT; j++)
        if (bk[j] >= 0) brec[grun[bk[j]] + rank[j]] = make_int2(src[j], dst[j]);
}

// one block per bucket (256 nodes): count per node in LDS, scan, emit
// row_start + dinv, then place sources into final CSR order.
__global__ __launch_bounds__(256)
void node_sort(const int2* __restrict__ brec, const int* __restrict__ bucket_off,
               int* __restrict__ row_start, float* __restrict__ dinv,
               int* __restrict__ esrc) {
    __shared__ int cnt[256];
    __shared__ int s[256];
    __shared__ int cur[256];
    const int tid = threadIdx.x;
    const int b = blockIdx.x;
    cnt[tid] = 0;
    __syncthreads();
    const int off = bucket_off[b];
    const int end = bucket_off[b + 1];
    for (int i = off + tid; i < end; i += 256)
        atomicAdd(&cnt[brec[i].y & 255], 1);
    __syncthreads();
    const int v = cnt[tid];
    s[tid] = v;
    __syncthreads();
    for (int o = 1; o < 256; o <<= 1) {
        int t = (tid >= o) ? s[tid - o] : 0;
        __syncthreads();
        s[tid] += t;
        __syncthreads();
    }
    const int gpos = off + s[tid] - v;   // this node's start in final CSR
    cur[tid] = gpos;
    const int node = b * 256 + tid;
    if (node < N_NODES) {
        row_start[node] = gpos;
        dinv[node] = rsqrtf(1.0f + (float)v);
    }
    if (b == NBUCK - 1 && tid == 0) row_start[N_NODES] = N_EDGES;
    __syncthreads();
    for (int i = off + tid; i < end; i += 256) {
        int2 rec = brec[i];
        int p = atomicAdd(&cur[rec.y & 255], 1);
        esrc[p] = rec.x;
    }
}

// ---------------- fp16 prep ----------------

__global__ void convert_x(const float* __restrict__ x, _Float16* __restrict__ xh) {
    int i = blockIdx.x * 256 + threadIdx.x;   // one float4 per thread
    if (i < N_NODES * (HID / 4)) {
        float4 v = ((const float4*)x)[i];
        union { __half2 h2[2]; int2 i2; } u;
        u.h2[0] = __floats2half2_rn(v.x, v.y);
        u.h2[1] = __floats2half2_rn(v.z, v.w);
        ((int2*)xh)[i] = u.i2;
    }
}

// all four weights -> fp16, transposed to [N][K]
__global__ void wtrans_all(const float* __restrict__ W1, const float* __restrict__ W2,
                           const float* __restrict__ W3, const float* __restrict__ Wo,
                           _Float16* __restrict__ wt1, _Float16* __restrict__ wt2,
                           _Float16* __restrict__ wt3, _Float16* __restrict__ wto) {
    const int SZ = HID * HID;  // 16384
    int i = blockIdx.x * 256 + threadIdx.x;
    if (i < SZ) {
        int k = i >> 7, c = i & 127;
        wt1[(size_t)c * HID + k] = (_Float16)W1[i];
    } else if (i < 2 * SZ) {
        int j = i - SZ, k = j >> 7, c = j & 127;
        wt2[(size_t)c * HID + k] = (_Float16)W2[j];
    } else if (i < 3 * SZ) {
        int j = i - 2 * SZ, k = j >> 7, c = j & 127;
        wt3[(size_t)c * HID + k] = (_Float16)W3[j];
    } else if (i < 3 * SZ + HID * OUT_CH) {
        int j = i - 3 * SZ, k = j >> 6, c = j & 63;
        wto[(size_t)c * HID + k] = (_Float16)Wo[j];
    }
}

// ---------------- MFMA GEMM: Y[n][OUT] = A(fp16)[n][128] @ W, Wt is [OUT][128] ----------------
// Wave = 16 rows x 64 cols (4 16x16 tiles, K=128 -> 4 MFMA each). No LDS, no syncs.

template <int OUT, bool ADD_BIAS, bool SCALE, bool HALF_OUT>
__global__ __launch_bounds__(256)
void gemm_mfma(const _Float16* __restrict__ A, const _Float16* __restrict__ Wt,
               const float* __restrict__ bias, const float* __restrict__ dinv,
               void* __restrict__ Yv, int n) {
    const int tid  = threadIdx.x;
    const int lane = tid & 63;
    const int wv   = tid >> 6;
    const int m0   = blockIdx.x * 64 + wv * 16;
    if (m0 >= n) return;                       // n % 16 == 0: no partial bands
    const int l15  = lane & 15;
    const int kb   = lane >> 4;                // 0..3
    const int col0 = blockIdx.y * 64;

    const _Float16* arow = A + (size_t)(m0 + l15) * 128 + kb * 8;
    half8 a[4];
#pragma unroll
    for (int j = 0; j < 4; j++) a[j] = *(const half8*)(arow + j * 32);

    const int rbase = m0 + kb * 4;             // rows this lane's D covers
    float4 dv = make_float4(1.f, 1.f, 1.f, 1.f);
    if constexpr (SCALE) dv = *(const float4*)(dinv + rbase);
    const float ds[4] = {dv.x, dv.y, dv.z, dv.w};

#pragma unroll
    for (int nt = 0; nt < 4; nt++) {
        const int col = col0 + nt * 16 + l15;
        const _Float16* brow = Wt + (size_t)col * 128 + kb * 8;
        floatx4 acc = {0.f, 0.f, 0.f, 0.f};
#pragma unroll
        for (int j = 0; j < 4; j++) {
            half8 b = *(const half8*)(brow + j * 32);
            acc = __builtin_amdgcn_mfma_f32_16x16x32_f16(a[j], b, acc, 0, 0, 0);
        }
        if constexpr (HALF_OUT) {
            _Float16* Y = (_Float16*)Yv;
#pragma unroll
            for (int r = 0; r < 4; r++)
                Y[(size_t)(rbase + r) * OUT + col] = (_Float16)(acc[r] * ds[r]);
        } else {
            float* Y = (float*)Yv;
            float bc = ADD_BIAS ? bias[col] : 0.f;
#pragma unroll
            for (int r = 0; r < 4; r++)
                Y[(size_t)(rbase + r) * OUT + col] = acc[r] + bc;
        }
    }
}

// ---------------- fused aggregation ----------------
// t is dinv-pre-scaled fp16. out[c] = relu(dinv[c]*(t[c] + sum_src t[src]) + b), fp16.

__global__ __launch_bounds__(256)
void aggregate_h(const _Float16* __restrict__ t, const int* __restrict__ row_start,
                 const int* __restrict__ esrc, const float* __restrict__ dinv,
                 const float* __restrict__ bias, _Float16* __restrict__ out) {
    const int tid = threadIdx.x;
    const int node = blockIdx.x * 8 + (tid >> 5);
    const int f4 = tid & 31;   // features 4*f4 .. 4*f4+3
    if (node >= N_NODES) return;

    const int2* t2 = (const int2*)t;

    int2 sg = t2[(size_t)node * 32 + f4];       // self term (pre-scaled)
    float2 slo = __half22float2(*(__half2*)&sg.x);
    float2 shi = __half22float2(*(__half2*)&sg.y);
    float4 acc = make_float4(slo.x, slo.y, shi.x, shi.y);

    int k = row_start[node];
    const int k1 = row_start[node + 1];
    for (; k + 8 <= k1; k += 8) {
        int src[8];
#pragma unroll
        for (int u = 0; u < 8; u++) src[u] = esrc[k + u];
        int2 g[8];
#pragma unroll
        for (int u = 0; u < 8; u++) g[u] = t2[(size_t)src[u] * 32 + f4];
#pragma unroll
        for (int u = 0; u < 8; u++) {
            float2 lo = __half22float2(*(__half2*)&g[u].x);
            float2 hi = __half22float2(*(__half2*)&g[u].y);
            acc.x += lo.x;
            acc.y += lo.y;
            acc.z += hi.x;
            acc.w += hi.y;
        }
    }
    for (; k < k1; k++) {
        int2 g = t2[(size_t)esrc[k] * 32 + f4];
        float2 lo = __half22float2(*(__half2*)&g.x);
        float2 hi = __half22float2(*(__half2*)&g.y);
        acc.x += lo.x;
        acc.y += lo.y;
        acc.z += hi.x;
        acc.w += hi.y;
    }

    const float d = dinv[node];
    float4 b = ((const float4*)bias)[f4];
    acc.x = fmaxf(acc.x * d + b.x, 0.f);
    acc.y = fmaxf(acc.y * d + b.y, 0.f);
    acc.z = fmaxf(acc.z * d + b.z, 0.f);
    acc.w = fmaxf(acc.w * d + b.w, 0.f);

    union { __half2 h2[2]; int2 i2; } u;
    u.h2[0] = __floats2half2_rn(acc.x, acc.y);
    u.h2[1] = __floats2half2_rn(acc.z, acc.w);
    ((int2*)out)[(size_t)node * 32 + f4] = u.i2;
}

// ---------------- mean pool ----------------

__global__ __launch_bounds__(256)
void mean_partial(const float* __restrict__ P, float* __restrict__ sum) {
    __shared__ float red[256];
    const int tid = threadIdx.x;
    const int c = tid & 63;
    const int grp = tid >> 6;
    float acc = 0.0f;
    for (int r = blockIdx.x * 4 + grp; r < N_NODES; r += gridDim.x * 4)
        acc += P[r * OUT_CH + c];
    red[tid] = acc;
    __syncthreads();
    if (grp == 0) {
        float s = red[c] + red[64 + c] + red[128 + c] + red[192 + c];
        atomicAdd(&sum[c], s);
    }
}

__global__ void mean_final(const float* __restrict__ sum, float* __restrict__ out) {
    int j = threadIdx.x;
    if (j < OUT_CH) out[N_NODES * OUT_CH + j] = sum[j] * (1.0f / N_NODES);
}

// ---------------- launch ----------------

extern "C" void kernel_launch(void* const* d_in, const int* in_sizes, int n_in,
                              void* d_out, int out_size, void* d_ws, size_t ws_size,
                              hipStream_t stream) {
    const float* x  = (const float*)d_in[0];
    const int* ei   = (const int*)d_in[1];   // int32 on device
    const float* W1 = (const float*)d_in[2];
    const float* b1 = (const float*)d_in[3];
    const float* W2 = (const float*)d_in[4];
    const float* b2 = (const float*)d_in[5];
    const float* W3 = (const float*)d_in[6];
    const float* b3 = (const float*)d_in[7];
    const float* Wo = (const float*)d_in[8];
    const float* bo = (const float*)d_in[9];
    float* out = (float*)d_out;

    char* ws = (char*)d_ws;
    auto take = [&](size_t bytes) {
        char* p = ws;
        ws += (bytes + 255) & ~size_t(255);
        return (void*)p;
    };
    int*      bhist      = (int*)take((size_t)HB * NBUCK * 4);
    int*      bucket_off = (int*)take((size_t)(NBUCK + 1) * 4);
    int*      bucket_cur = (int*)take((size_t)NBUCK * 4);
    int2*     brec       = (int2*)take((size_t)N_EDGES * 8);
    int*      row_start  = (int*)take((size_t)(N_NODES + 1) * 4);
    float*    dinv       = (float*)take((size_t)N_NODES * 4);
    int*      esrc       = (int*)take((size_t)N_EDGES * 4);
    float*    sum        = (float*)take(OUT_CH * 4);
    _Float16* xh         = (_Float16*)take((size_t)N_NODES * HID * 2);
    _Float16* wt1        = (_Float16*)take((size_t)HID * HID * 2);
    _Float16* wt2        = (_Float16*)take((size_t)HID * HID * 2);
    _Float16* wt3        = (_Float16*)take((size_t)HID * HID * 2);
    _Float16* wto        = (_Float16*)take((size_t)HID * OUT_CH * 2);
    _Float16* hA         = (_Float16*)take((size_t)N_NODES * HID * 2);
    _Float16* hB         = (_Float16*)take((size_t)N_NODES * HID * 2);

    const int BS = 256;
    const int gScat = (N_EDGES + BS * EPT - 1) / (BS * EPT);
    const int gGemm = (N_NODES + 63) / 64;
    const int gAgg  = (N_NODES + 7) / 8;
    const int gCvt  = (N_NODES * (HID / 4) + BS - 1) / BS;
    const int gWt   = (3 * HID * HID + HID * OUT_CH + BS - 1) / BS;

    // CSR build (bucketed, write-coalesced, no per-node global atomics)
    bucket_hist<<<HB, BS, 0, stream>>>(ei, bhist);
    bucket_scan<<<1, BS, 0, stream>>>(bhist, bucket_off, bucket_cur, sum);
    bucket_scatter<<<gScat, BS, 0, stream>>>(ei, bucket_cur, brec);
    node_sort<<<NBUCK, BS, 0, stream>>>(brec, bucket_off, row_start, dinv, esrc);

    // fp16 prep
    convert_x<<<gCvt, BS, 0, stream>>>(x, xh);
    wtrans_all<<<gWt, BS, 0, stream>>>(W1, W2, W3, Wo, wt1, wt2, wt3, wto);

    const _Float16* hin = xh;
    const _Float16* wts[3] = {wt1, wt2, wt3};
    const float* bs[3] = {b1, b2, b3};
    for (int layer = 0; layer < 3; layer++) {
        gemm_mfma<HID, false, true, true><<<dim3(gGemm, 2), BS, 0, stream>>>(
            hin, wts[layer], nullptr, dinv, hA, N_NODES);
        aggregate_h<<<gAgg, BS, 0, stream>>>(hA, row_start, esrc, dinv, bs[layer], hB);
        hin = hB;
    }

    gemm_mfma<OUT_CH, true, false, false><<<dim3(gGemm, 1), BS, 0, stream>>>(
        hB, wto, bo, nullptr, out, N_NODES);
    mean_partial<<<256, BS, 0, stream>>>(out, sum);
    mean_final<<<1, 64, 0, stream>>>(sum, out);
}